// Round 1
// baseline (675.512 us; speedup 1.0000x reference)
//
#include <hip/hip_runtime.h>

// Problem constants (reference: N=1e6, D=128, C=1024)
#define D_CONST 128
#define C_CONST 1024
#define LC_EPS  0.1f

// ---------------- main path (atomic-free hierarchical, fused finish) ----------------
#define G_HIST   512              // histogram blocks (2 per CU -> 100% occupancy)
#define TPB      1024             // threads per block, kernel 1 (16 waves)
#define WAVES_PB (TPB / 64)
#define RED_TPB  512              // reduce_final threads (one per histogram block)

typedef float f32x4 __attribute__((ext_vector_type(4)));

// ws layout (floats), main path:
//   [0 .. 3*C*G)            per-block partials, layout [stat][c][g]  (g coalesced!)
//   [3CG .. 3CG+G)          per-block lc partials
//   [3CG+G .. 3CG+2G)       per-block q partials
//   [3CG+2G .. +4)          accumulators: var_sum, lc_sum, q_sum, block counter(int)
#define P_OFF    0
#define LCQ_OFF  (3 * C_CONST * G_HIST)
#define ACC_OFF  (LCQ_OFF + 2 * G_HIST)
#define MAIN_WS_FLOATS (ACC_OFF + 4)

// One wave processes 2 rows per "pair": 64 lanes x float4 = 1024 B = 2 rows.
// lanes 0-31 -> row 2*pair, lanes 32-63 -> row 2*pair+1.
// sub<16 -> dims<64 (J=+1), sub>=16 -> dims>=64 (J=-1).
// xor 1..16 stays within each 32-lane half -> 5 shuffles reduce BOTH rows.
__global__ __launch_bounds__(TPB, 8) void qstat_main(const float* __restrict__ z,
                                                     const int* __restrict__ labels,
                                                     float* __restrict__ ws,
                                                     int n) {
    __shared__ float h[3 * C_CONST];            // cnt | sum q | sum q^2
    __shared__ float wred[2 * WAVES_PB];

    // zero the cross-kernel accumulators (stream order guarantees visibility
    // to reduce_final; ws is re-poisoned every call so this must happen here)
    if (blockIdx.x == 0 && threadIdx.x < 4) ws[ACC_OFF + threadIdx.x] = 0.0f;

    for (int i = threadIdx.x; i < 3 * C_CONST; i += TPB) h[i] = 0.0f;
    __syncthreads();

    const int lane = threadIdx.x & 63;
    const int wv   = threadIdx.x >> 6;
    const int gw   = blockIdx.x * WAVES_PB + wv;
    const int nw   = G_HIST * WAVES_PB;         // total waves in grid
    const int half = lane >> 5;
    const int sub  = lane & 31;
    const float sign = (sub < 16) ? 1.0f : -1.0f;

    float lc_acc = 0.0f;
    float q_acc  = 0.0f;

    const int n_pairs = n >> 1;                 // n is even (1e6)

    // unrolled x2: two independent 1KB nontemporal loads in flight per wave
    for (int base = gw * 2; base < n_pairs; base += nw * 2) {
        const int pair1 = base + 1;
        const bool has1 = pair1 < n_pairs;

        const int row0 = base * 2 + half;
        const f32x4* zp0 = (const f32x4*)(z + (long long)row0 * D_CONST);
        const f32x4 v0 = __builtin_nontemporal_load(zp0 + sub);
        f32x4 v1;
        int row1 = 0;
        if (has1) {
            row1 = pair1 * 2 + half;
            const f32x4* zp1 = (const f32x4*)(z + (long long)row1 * D_CONST);
            v1 = __builtin_nontemporal_load(zp1 + sub);
        }

        float s0 = (v0.x * v0.x + v0.y * v0.y + v0.z * v0.z + v0.w * v0.w) * sign;
        s0 += __shfl_xor(s0, 1);
        s0 += __shfl_xor(s0, 2);
        s0 += __shfl_xor(s0, 4);
        s0 += __shfl_xor(s0, 8);
        s0 += __shfl_xor(s0, 16);
        if (sub == 0) {
            const float q = s0;
            lc_acc += fmaxf(LC_EPS - fabsf(q), 0.0f);
            q_acc  += q;
            const int c = labels[row0];
            atomicAdd(&h[c], 1.0f);
            atomicAdd(&h[C_CONST + c], q);
            atomicAdd(&h[2 * C_CONST + c], q * q);
        }

        if (has1) {
            float s1 = (v1.x * v1.x + v1.y * v1.y + v1.z * v1.z + v1.w * v1.w) * sign;
            s1 += __shfl_xor(s1, 1);
            s1 += __shfl_xor(s1, 2);
            s1 += __shfl_xor(s1, 4);
            s1 += __shfl_xor(s1, 8);
            s1 += __shfl_xor(s1, 16);
            if (sub == 0) {
                const float q = s1;
                lc_acc += fmaxf(LC_EPS - fabsf(q), 0.0f);
                q_acc  += q;
                const int c = labels[row1];
                atomicAdd(&h[c], 1.0f);
                atomicAdd(&h[C_CONST + c], q);
                atomicAdd(&h[2 * C_CONST + c], q * q);
            }
        }
    }

    // fold the two per-wave partial holders (lanes 0 and 32)
    lc_acc += __shfl_xor(lc_acc, 32);
    q_acc  += __shfl_xor(q_acc, 32);
    if (lane == 0) { wred[wv] = lc_acc; wred[WAVES_PB + wv] = q_acc; }
    __syncthreads();   // also makes all LDS-hist atomics visible

    if (threadIdx.x == 0) {
        float l = 0.0f, q = 0.0f;
        for (int i = 0; i < WAVES_PB; i++) { l += wred[i]; q += wred[WAVES_PB + i]; }
        ws[LCQ_OFF + blockIdx.x]          = l;
        ws[LCQ_OFF + G_HIST + blockIdx.x] = q;
    }

    // transposed flush: [stat][c][g] so the reducer reads coalesced.
    // scattered 4B stores here are fire-and-forget and hide under the tail.
    for (int i = threadIdx.x; i < 3 * C_CONST; i += TPB) {
        const int stat = i >> 10;          // C_CONST == 1024
        const int c    = i & (C_CONST - 1);
        ws[P_OFF + stat * (C_CONST * G_HIST) + c * G_HIST + blockIdx.x] = h[i];
    }
}

// One block per class: coalesced-sum the G partials, emit per-class variance,
// fold everything into out[0] via device atomics + last-block pattern.
__global__ __launch_bounds__(RED_TPB) void reduce_final(float* __restrict__ ws,
                                                        float* __restrict__ out,
                                                        int n) {
    const int c = blockIdx.x;
    const int t = threadIdx.x;          // 0..G_HIST-1 (coalesced over g)
    const float* p = ws + P_OFF;
    float cnt = p[0 * C_CONST * G_HIST + c * G_HIST + t];
    float s   = p[1 * C_CONST * G_HIST + c * G_HIST + t];
    float s2  = p[2 * C_CONST * G_HIST + c * G_HIST + t];
    float lcv = 0.0f, qv = 0.0f;
    if (c == 0) {                        // block 0 also reduces lc/q partials
        lcv = ws[LCQ_OFF + t];
        qv  = ws[LCQ_OFF + G_HIST + t];
    }

    for (int m = 1; m < 64; m <<= 1) {
        cnt += __shfl_xor(cnt, m);
        s   += __shfl_xor(s, m);
        s2  += __shfl_xor(s2, m);
        lcv += __shfl_xor(lcv, m);
        qv  += __shfl_xor(qv, m);
    }
    __shared__ float r[5][RED_TPB / 64];
    const int wv = t >> 6;
    if ((t & 63) == 0) { r[0][wv] = cnt; r[1][wv] = s; r[2][wv] = s2;
                         r[3][wv] = lcv; r[4][wv] = qv; }
    __syncthreads();
    if (t == 0) {
        float C0 = 0, S0 = 0, S20 = 0, L0 = 0, Q0 = 0;
        for (int i = 0; i < RED_TPB / 64; i++) {
            C0 += r[0][i]; S0 += r[1][i]; S20 += r[2][i]; L0 += r[3][i]; Q0 += r[4][i];
        }
        const float cc = fmaxf(C0, 1.0f);
        // segment_sum((q-m)^2)/cnt == (s2 - s^2/cnt)/cnt  (exact identity)
        atomicAdd(&ws[ACC_OFF + 0], (S20 - S0 * S0 / cc) / cc);
        if (c == 0) {
            atomicAdd(&ws[ACC_OFF + 1], L0);
            atomicAdd(&ws[ACC_OFF + 2], Q0);
        }
        __threadfence();                  // order acc adds before the counter
        const int old = atomicAdd((int*)(ws + ACC_OFF + 3), 1);
        if (old == C_CONST - 1) {         // last block: everything is visible
            const float v = atomicAdd(&ws[ACC_OFF + 0], 0.0f);
            const float l = atomicAdd(&ws[ACC_OFF + 1], 0.0f);
            const float q = atomicAdd(&ws[ACC_OFF + 2], 0.0f);
            const float mq = q / (float)n;
            out[0] = l / (float)n + v / (float)C_CONST + mq * mq;
        }
    }
}

// ---------------- fallback path (round-1, known-correct, small ws) ----------------
#define FB_WS_FLOATS (3 * C_CONST + 2)

__global__ __launch_bounds__(256) void qstat_fb(const float* __restrict__ z,
                                                const int* __restrict__ labels,
                                                float* __restrict__ ws,
                                                int n) {
    const int lane = threadIdx.x & 63;
    const long long gw = (long long)blockIdx.x * 4 + (threadIdx.x >> 6);
    const long long nw = (long long)gridDim.x * 4;
    const int half = lane >> 5, sub = lane & 31;
    const float sign = (sub < 16) ? 1.0f : -1.0f;
    float lc = 0.0f, qa = 0.0f;
    const long long n_pairs = (long long)n >> 1;
    for (long long pair = gw; pair < n_pairs; pair += nw) {
        const long long row = pair * 2 + half;
        float4 v = ((const float4*)(z + row * D_CONST))[sub];
        float s = (v.x * v.x + v.y * v.y + v.z * v.z + v.w * v.w) * sign;
        s += __shfl_xor(s, 1); s += __shfl_xor(s, 2); s += __shfl_xor(s, 4);
        s += __shfl_xor(s, 8); s += __shfl_xor(s, 16);
        if (sub == 0) {
            lc += fmaxf(LC_EPS - fabsf(s), 0.0f); qa += s;
            const int c = labels[row];
            atomicAdd(&ws[c], 1.0f);
            atomicAdd(&ws[C_CONST + c], s);
            atomicAdd(&ws[2 * C_CONST + c], s * s);
        }
    }
    lc += __shfl_xor(lc, 32); qa += __shfl_xor(qa, 32);
    if (lane == 0) {
        atomicAdd(&ws[3 * C_CONST], lc);
        atomicAdd(&ws[3 * C_CONST + 1], qa);
    }
}

__global__ __launch_bounds__(C_CONST) void finalize_fb(const float* __restrict__ ws,
                                                       float* __restrict__ out, int n) {
    __shared__ float red[C_CONST];
    const int c = threadIdx.x;
    const float cnt = fmaxf(ws[c], 1.0f);
    const float s = ws[C_CONST + c], s2 = ws[2 * C_CONST + c];
    red[c] = (s2 - s * s / cnt) / cnt;
    __syncthreads();
    for (int off = C_CONST / 2; off > 0; off >>= 1) {
        if (c < off) red[c] += red[c + off];
        __syncthreads();
    }
    if (c == 0) {
        out[0] = ws[3 * C_CONST] / (float)n + red[0] / (float)C_CONST
               + (ws[3 * C_CONST + 1] / (float)n) * (ws[3 * C_CONST + 1] / (float)n);
    }
}

extern "C" void kernel_launch(void* const* d_in, const int* in_sizes, int n_in,
                              void* d_out, int out_size, void* d_ws, size_t ws_size,
                              hipStream_t stream) {
    const float* z      = (const float*)d_in[0];
    const int*   labels = (const int*)d_in[1];
    // d_in[2] is J: +1 on first 64 dims, -1 on last 64 — baked into `sign`.
    float* ws  = (float*)d_ws;
    float* out = (float*)d_out;
    const int n = in_sizes[1];   // N rows

    if (ws_size >= (size_t)MAIN_WS_FLOATS * sizeof(float)) {
        // atomic-free hierarchical path; every ws word read is written first
        // each call (ACC words zeroed by qstat_main block 0), so no memset.
        qstat_main<<<G_HIST, TPB, 0, stream>>>(z, labels, ws, n);
        reduce_final<<<C_CONST, RED_TPB, 0, stream>>>(ws, out, n);
    } else {
        hipMemsetAsync(ws, 0, FB_WS_FLOATS * sizeof(float), stream);
        qstat_fb<<<2048, 256, 0, stream>>>(z, labels, ws, n);
        finalize_fb<<<1, C_CONST, 0, stream>>>(ws, out, n);
    }
}

// Round 2
// 653.663 us; speedup vs baseline: 1.0334x; 1.0334x over previous
//
#include <hip/hip_runtime.h>

// Problem constants (reference: N=1e6, D=128, C=1024)
#define D_CONST 128
#define C_CONST 1024
#define LC_EPS  0.1f

#define G_HIST   512              // histogram blocks (2 per CU -> 100% occupancy)
#define TPB      1024             // threads per block, kernel 1 (16 waves)
#define WAVES_PB (TPB / 64)

// ws layout (floats):
//   [0 .. C)        per-class count
//   [C .. 2C)       per-class sum q
//   [2C .. 3C)      per-class sum q^2
//   [3C]            lc sum
//   [3C+1]          q sum
#define WS_FLOATS (3 * C_CONST + 2)

// One wave processes 2 rows per "pair": 64 lanes x float4 = 1024 B = 2 rows.
// lanes 0-31 -> row 2*pair, lanes 32-63 -> row 2*pair+1.
// sub<16 -> dims<64 (J=+1), sub>=16 -> dims>=64 (J=-1).
// xor 1..16 stays within each 32-lane half -> 5 shuffles reduce BOTH rows.
__global__ __launch_bounds__(TPB, 8) void qstat_main(const float* __restrict__ z,
                                                     const int* __restrict__ labels,
                                                     float* __restrict__ ws,
                                                     int n) {
    __shared__ float h[3 * C_CONST];            // cnt | sum q | sum q^2
    __shared__ float wred[2 * WAVES_PB];

    for (int i = threadIdx.x; i < 3 * C_CONST; i += TPB) h[i] = 0.0f;
    __syncthreads();

    const int lane = threadIdx.x & 63;
    const int wv   = threadIdx.x >> 6;
    const int gw   = blockIdx.x * WAVES_PB + wv;
    const int nw   = G_HIST * WAVES_PB;         // total waves in grid
    const int half = lane >> 5;
    const int sub  = lane & 31;
    const float sign = (sub < 16) ? 1.0f : -1.0f;

    float lc_acc = 0.0f;
    float q_acc  = 0.0f;

    const int n_pairs = n >> 1;                 // n is even (1e6)

    // unrolled x2: two independent 1KB loads in flight per wave
    for (int base = gw * 2; base < n_pairs; base += nw * 2) {
        const int pair1 = base + 1;
        const bool has1 = pair1 < n_pairs;

        const int row0 = base * 2 + half;
        const float4 v0 = ((const float4*)(z + (long long)row0 * D_CONST))[sub];
        float4 v1;
        int row1 = 0;
        if (has1) {
            row1 = pair1 * 2 + half;
            v1 = ((const float4*)(z + (long long)row1 * D_CONST))[sub];
        }

        // hoist label loads above the shuffle chains so their latency overlaps
        int c0 = 0, c1 = 0;
        if (sub == 0) {
            c0 = labels[row0];
            if (has1) c1 = labels[row1];
        }

        float s0 = (v0.x * v0.x + v0.y * v0.y + v0.z * v0.z + v0.w * v0.w) * sign;
        s0 += __shfl_xor(s0, 1);
        s0 += __shfl_xor(s0, 2);
        s0 += __shfl_xor(s0, 4);
        s0 += __shfl_xor(s0, 8);
        s0 += __shfl_xor(s0, 16);
        if (sub == 0) {
            const float q = s0;
            lc_acc += fmaxf(LC_EPS - fabsf(q), 0.0f);
            q_acc  += q;
            atomicAdd(&h[c0], 1.0f);
            atomicAdd(&h[C_CONST + c0], q);
            atomicAdd(&h[2 * C_CONST + c0], q * q);
        }

        if (has1) {
            float s1 = (v1.x * v1.x + v1.y * v1.y + v1.z * v1.z + v1.w * v1.w) * sign;
            s1 += __shfl_xor(s1, 1);
            s1 += __shfl_xor(s1, 2);
            s1 += __shfl_xor(s1, 4);
            s1 += __shfl_xor(s1, 8);
            s1 += __shfl_xor(s1, 16);
            if (sub == 0) {
                const float q = s1;
                lc_acc += fmaxf(LC_EPS - fabsf(q), 0.0f);
                q_acc  += q;
                atomicAdd(&h[c1], 1.0f);
                atomicAdd(&h[C_CONST + c1], q);
                atomicAdd(&h[2 * C_CONST + c1], q * q);
            }
        }
    }

    // fold the two per-wave partial holders (lanes 0 and 32)
    lc_acc += __shfl_xor(lc_acc, 32);
    q_acc  += __shfl_xor(q_acc, 32);
    if (lane == 0) { wred[wv] = lc_acc; wred[WAVES_PB + wv] = q_acc; }
    __syncthreads();   // also makes all LDS-hist atomics visible

    if (threadIdx.x == 0) {
        float l = 0.0f, q = 0.0f;
        for (int i = 0; i < WAVES_PB; i++) { l += wred[i]; q += wred[WAVES_PB + i]; }
        atomicAdd(&ws[3 * C_CONST], l);
        atomicAdd(&ws[3 * C_CONST + 1], q);
    }

    // flush the block histogram straight into the global per-class stats.
    // 512 serialized f32 adds per word at L2, 3072 words across all channels
    // in parallel -> ~1-2 us total; kills the 6.3 MB ws round-trip and the
    // 1024-block reducer kernel of the previous version.
    for (int i = threadIdx.x; i < 3 * C_CONST; i += TPB) {
        atomicAdd(&ws[i], h[i]);
    }
}

// Single 1024-thread block: per-class variance + fold lc/q into the scalar.
// Cross-kernel visibility is guaranteed by stream ordering (launch boundary).
__global__ __launch_bounds__(C_CONST) void finalize_main(const float* __restrict__ ws,
                                                         float* __restrict__ out,
                                                         int n) {
    __shared__ float red[C_CONST];
    const int c = threadIdx.x;
    const float cnt = fmaxf(ws[c], 1.0f);
    const float s   = ws[C_CONST + c];
    const float s2  = ws[2 * C_CONST + c];
    // segment_sum((q-m)^2)/cnt == (s2 - s^2/cnt)/cnt  (exact identity)
    red[c] = (s2 - s * s / cnt) / cnt;
    __syncthreads();
    for (int off = C_CONST / 2; off > 0; off >>= 1) {
        if (c < off) red[c] += red[c + off];
        __syncthreads();
    }
    if (c == 0) {
        const float lc = ws[3 * C_CONST] / (float)n;
        const float mq = ws[3 * C_CONST + 1] / (float)n;
        out[0] = lc + red[0] / (float)C_CONST + mq * mq;
    }
}

extern "C" void kernel_launch(void* const* d_in, const int* in_sizes, int n_in,
                              void* d_out, int out_size, void* d_ws, size_t ws_size,
                              hipStream_t stream) {
    const float* z      = (const float*)d_in[0];
    const int*   labels = (const int*)d_in[1];
    // d_in[2] is J: +1 on first 64 dims, -1 on last 64 — baked into `sign`.
    float* ws  = (float*)d_ws;
    float* out = (float*)d_out;
    const int n = in_sizes[1];   // N rows

    // ws is poisoned each call; the atomic accumulators need a zero base.
    hipMemsetAsync(ws, 0, WS_FLOATS * sizeof(float), stream);
    qstat_main<<<G_HIST, TPB, 0, stream>>>(z, labels, ws, n);
    finalize_main<<<1, C_CONST, 0, stream>>>(ws, out, n);
}